// Round 12
// baseline (37.798 us; speedup 1.0000x reference)
//
#include <hip/hip_runtime.h>

#define B 256
#define N 2048
#define P 2048
#define C 10
#define S_CHUNKS 4
#define PPB (P / S_CHUNKS)     // 512 pairs per block
#define NIT (PPB / 32)         // 16 iterations; 32 pairs per block-iter
#define LN_EPS 1e-5f

typedef float v2f __attribute__((ext_vector_type(2)));
typedef _Float16 h2 __attribute__((ext_vector_type(2)));

// ---- f16 helpers: builtins with safe fallbacks (no hand-written asm) -------
static __device__ __forceinline__ float fdot2(h2 a, h2 b, float c) {
#if __has_builtin(__builtin_amdgcn_fdot2)
    return __builtin_amdgcn_fdot2(a, b, c, false);   // v_dot2_f32_f16
#else
    return (float)a.x * (float)b.x + (float)a.y * (float)b.y + c;
#endif
}
static __device__ __forceinline__ h2 h2fma(h2 a, h2 b, h2 c) {
#if __has_builtin(__builtin_elementwise_fma)
    return __builtin_elementwise_fma(a, b, c);        // v_pk_fma_f16
#else
    return a * b + c;
#endif
}
static __device__ __forceinline__ h2 h2relu(h2 x) {
#if __has_builtin(__builtin_elementwise_max)
    return __builtin_elementwise_max(x, h2{(_Float16)0.f, (_Float16)0.f});
#else
    h2 r;
    r.x = x.x > (_Float16)0.f ? x.x : (_Float16)0.f;
    r.y = x.y > (_Float16)0.f ? x.y : (_Float16)0.f;
    return r;
#endif
}
static __device__ __forceinline__ h2 pkrtz(float a, float b) {
#if __has_builtin(__builtin_amdgcn_cvt_pkrtz)
    return __builtin_bit_cast(h2, __builtin_amdgcn_cvt_pkrtz(a, b));  // v_cvt_pkrtz_f16_f32
#else
    return h2{(_Float16)a, (_Float16)b};
#endif
}
static __device__ __forceinline__ unsigned pk_rne(float a, float b) {
    return __builtin_bit_cast(unsigned, h2{(_Float16)a, (_Float16)b});
}

// ---- 16-lane all-reduce sum via DPP butterfly (proven R2..R11) -------------
static __device__ __forceinline__ float red16(float x) {
    x += __int_as_float(__builtin_amdgcn_update_dpp(0, __float_as_int(x), 0xB1,  0xF, 0xF, true));
    x += __int_as_float(__builtin_amdgcn_update_dpp(0, __float_as_int(x), 0x4E,  0xF, 0xF, true));
    x += __int_as_float(__builtin_amdgcn_update_dpp(0, __float_as_int(x), 0x141, 0xF, 0xF, true));
    x += __int_as_float(__builtin_amdgcn_update_dpp(0, __float_as_int(x), 0x140, 0xF, 0xF, true));
    return x;
}

// ---------------------------------------------------------------------------
// Kernel 1 (unchanged from R11): every block redundantly reduces the 6
// variance-quadratic scalars; block 0 writes the f16-packed per-sublane
// weight table; all blocks write T = {pk(rs*x0, rs*x1), pk(rs, 1)}.
// ---------------------------------------------------------------------------
__global__ __launch_bounds__(256) void triple_kernel(
        const float* __restrict__ X,
        const float* __restrict__ W1, const float* __restrict__ b1,
        const float* __restrict__ gamma, const float* __restrict__ beta,
        unsigned* __restrict__ wsw, uint2* __restrict__ T) {
    const int t = threadIdx.x;
    __shared__ float r[6][128];
    __shared__ float sc[6];

    float w0 = 0.f, w1 = 0.f, bb = 0.f;
    if (t < 128) {
        w0 = W1[t]; w1 = W1[128 + t]; bb = b1[t];
        r[0][t] = w0; r[1][t] = w1; r[2][t] = bb;
    }
    __syncthreads();
    for (int s = 64; s > 0; s >>= 1) {
        if (t < s) { r[0][t] += r[0][t + s]; r[1][t] += r[1][t + s]; r[2][t] += r[2][t + s]; }
        __syncthreads();
    }
    const float m0 = r[0][0] * (1.f / 128.f);
    const float m1 = r[1][0] * (1.f / 128.f);
    const float mb = r[2][0] * (1.f / 128.f);
    __syncthreads();
    float c0 = 0.f, c1 = 0.f, cb = 0.f;
    if (t < 128) {
        c0 = w0 - m0; c1 = w1 - m1; cb = bb - mb;
        r[0][t] = c0 * c0; r[1][t] = c1 * c1; r[2][t] = cb * cb;
        r[3][t] = c0 * c1; r[4][t] = c0 * cb; r[5][t] = c1 * cb;
    }
    __syncthreads();
    for (int s = 64; s > 0; s >>= 1) {
        if (t < s) {
            #pragma unroll
            for (int q = 0; q < 6; ++q) r[q][t] += r[q][t + s];
        }
        __syncthreads();
    }
    if (t < 6) sc[t] = r[t][0] * (1.f / 128.f);
    __syncthreads();

    const float S00 = sc[0], S11 = sc[1], Sbb = sc[2];
    const float S01 = sc[3], S0b = sc[4], S1b = sc[5];

    if (t < 128) {
        const float g = gamma[t];
        r[0][t] = g * c0; r[1][t] = g * c1; r[2][t] = g * cb; r[3][t] = beta[t];
    }
    __syncthreads();
    if (blockIdx.x == 0 && t < 16) {
        uint4* dst = (uint4*)wsw + t * 4;
        #pragma unroll
        for (int m = 0; m < 4; ++m) {
            const int d0 = t + 32 * m, d1 = d0 + 16;
            dst[m] = uint4{pk_rne(r[0][d0], r[0][d1]), pk_rne(r[1][d0], r[1][d1]),
                           pk_rne(r[2][d0], r[2][d1]), pk_rne(r[3][d0], r[3][d1])};
        }
    }

    const int gid = blockIdx.x * 256 + t;       // 0 .. B*N-1
    const float2 x = ((const float2*)X)[gid];
    const float v = fmaf(x.x * x.x, S00, fmaf(x.y * x.y, S11, Sbb))
                  + 2.f * fmaf(x.x * x.y, S01, fmaf(x.x, S0b, x.y * S1b));
    const float rs = rsqrtf(v + LN_EPS);
    T[gid] = uint2{pk_rne(rs * x.x, rs * x.y), pk_rne(rs, 1.f)};
}

// ---------------------------------------------------------------------------
// Kernel 2 (R11 structure, NIT=16): 256 threads, grid (B, 4).
// 16-lane group handles 2 pair-streams per iter; sublane s owns d = s+32m
// (lo half) and d = s+32m+16 (hi half) as packed f16 pairs.
// ---------------------------------------------------------------------------
__global__ __launch_bounds__(256) void pair_kernel(
        const uint2*    __restrict__ T,
        const int*      __restrict__ pairs,
        const unsigned* __restrict__ wsw,
        float* __restrict__ part) {
    const int b = blockIdx.x;
    const int chunk = blockIdx.y;
    const int tid = threadIdx.x;
    const int w = tid >> 6, l = tid & 63, g = l >> 4, s = l & 15;
    const int slot = w * 4 + g;      // 0..15

    // per-lane packed f16 weights: 4x dwordx4
    const uint4* Wl = (const uint4*)wsw + s * 4;
    h2 gw0[4], gw1[4], gbc[4], be2[4];
    #pragma unroll
    for (int m = 0; m < 4; ++m) {
        const uint4 wm = Wl[m];
        gw0[m] = __builtin_bit_cast(h2, wm.x);
        gw1[m] = __builtin_bit_cast(h2, wm.y);
        gbc[m] = __builtin_bit_cast(h2, wm.z);
        be2[m] = __builtin_bit_cast(h2, wm.w);
    }

    const uint2* Tb  = T + (size_t)b * N;
    const int4*  pr4 = (const int4*)pairs;      // 2 pairs per int4
    const int i4base = chunk * (PPB / 2);

    v2f acc[4];
    #pragma unroll
    for (int m = 0; m < 4; ++m) acc[m] = v2f{0.f, 0.f};

    auto proc = [&](const uint2 ti, const uint2 tj) {
        const h2 abi = __builtin_bit_cast(h2, ti.x), ci = __builtin_bit_cast(h2, ti.y);
        const h2 abj = __builtin_bit_cast(h2, tj.x), cj = __builtin_bit_cast(h2, tj.y);
        const h2 aai = h2{abi.x, abi.x}, bbi = h2{abi.y, abi.y}, cci = h2{ci.x, ci.x};
        const h2 aaj = h2{abj.x, abj.x}, bbj = h2{abj.y, abj.y}, ccj = h2{cj.x, cj.x};
        h2 uu[4], vv[4];
        float nu = 0.f, nv = 0.f;
        #pragma unroll
        for (int m = 0; m < 4; ++m) {
            const h2 hi = h2relu(h2fma(aai, gw0[m], h2fma(bbi, gw1[m], h2fma(cci, gbc[m], be2[m]))));
            const h2 hj = h2relu(h2fma(aaj, gw0[m], h2fma(bbj, gw1[m], h2fma(ccj, gbc[m], be2[m]))));
            const h2 u = hi - hj;
            const h2 v = hi + hj;
            nu = fdot2(u, u, nu);
            nv = fdot2(v, v, nv);
            uu[m] = u; vv[m] = v;
        }
        nu = red16(nu);
        nv = red16(nv);
        const float ru = rsqrtf(fmaxf(nu, 1e-24f));
        const float rv = rsqrtf(fmaxf(nv, 1e-24f));
        const h2 ruv = pkrtz(ru, rv);
        #pragma unroll
        for (int m = 0; m < 4; ++m) {
            acc[m].x = fdot2(h2{uu[m].x, vv[m].x}, ruv, acc[m].x);
            acc[m].y = fdot2(h2{uu[m].y, vv[m].y}, ruv, acc[m].y);
        }
    };

    // software pipeline: idx prefetched 1 iter; stream-A data prefetched
    int4 idx = pr4[i4base + slot];
    uint2 tiA = Tb[idx.x], tjA = Tb[idx.y];

    for (int t = 0; t < NIT; ++t) {
        const uint2 tiB = Tb[idx.z], tjB = Tb[idx.w];
        int4 nidx = idx;
        if (t + 1 < NIT) nidx = pr4[i4base + (t + 1) * 16 + slot];

        proc(tiA, tjA);                          // stream A (prefetched data)

        const uint2 ntiA = Tb[nidx.x], ntjA = Tb[nidx.y];  // next A data

        proc(tiB, tjB);                          // stream B (loads hidden under A)

        idx = nidx; tiA = ntiA; tjA = ntjA;
    }

    // block reduce: 16 slots -> one 128-float partial (padded: conflict-free)
    __shared__ float red[16][8][17];
    #pragma unroll
    for (int m = 0; m < 4; ++m) {
        red[slot][2 * m    ][s] = acc[m].x;   // d = s + 32m
        red[slot][2 * m + 1][s] = acc[m].y;   // d = s + 32m + 16
    }
    __syncthreads();
    if (tid < 128) {
        const int ss = tid & 15, kk = tid >> 4;   // d = ss + 16*kk == tid
        float sum = 0.f;
        #pragma unroll
        for (int q = 0; q < 16; ++q) sum += red[q][kk][ss];
        part[((size_t)b * S_CHUNKS + chunk) * 128 + tid] = sum;
    }
}

// ---------------------------------------------------------------------------
// Kernel 3: reduce partials -> sdi, MLP head + mem logits.
// ---------------------------------------------------------------------------
__global__ __launch_bounds__(256) void head_kernel(
        const float* __restrict__ part,
        const float* __restrict__ Wm1, const float* __restrict__ bm1,
        const float* __restrict__ Wm2, const float* __restrict__ bm2,
        const float* __restrict__ mem,
        float* __restrict__ out_logits, float* __restrict__ out_sdi) {
    const int b = blockIdx.x;
    const int t = threadIdx.x;
    __shared__ float s[128];
    __shared__ float h[128];

    if (t < 128) {
        float sv = 0.f;
        #pragma unroll
        for (int k = 0; k < S_CHUNKS; ++k)
            sv += part[((size_t)b * S_CHUNKS + k) * 128 + t];
        sv *= (1.f / (2.f * P));
        s[t] = sv;
        out_sdi[(size_t)b * 128 + t] = sv;
    }
    __syncthreads();
    if (t < 128) {
        float a = bm1[t];
        for (int d = 0; d < 128; ++d) a = fmaf(s[d], Wm1[d * 128 + t], a);
        h[t] = fmaxf(a, 0.f);
    }
    __syncthreads();
    if (t < 16 * C) {                       // 160 threads: 16 lanes per class
        const int c = t >> 4, l = t & 15;
        float lg = 0.f;
        #pragma unroll
        for (int q = 0; q < 8; ++q) {
            const int d = l + 16 * q;
            lg = fmaf(s[d], mem[c * 128 + d], fmaf(h[d], Wm2[d * C + c], lg));
        }
        lg = red16(lg);
        if (l == 0) out_logits[(size_t)b * C + c] = lg + bm2[c];
    }
}

extern "C" void kernel_launch(void* const* d_in, const int* in_sizes, int n_in,
                              void* d_out, int out_size, void* d_ws, size_t ws_size,
                              hipStream_t stream) {
    const float* X     = (const float*)d_in[0];
    const int*   pairs = (const int*)  d_in[1];
    const float* W1    = (const float*)d_in[2];
    const float* b1    = (const float*)d_in[3];
    const float* gamma = (const float*)d_in[4];
    const float* beta  = (const float*)d_in[5];
    const float* Wm1   = (const float*)d_in[6];
    const float* bm1   = (const float*)d_in[7];
    const float* Wm2   = (const float*)d_in[8];
    const float* bm2   = (const float*)d_in[9];
    const float* mem   = (const float*)d_in[10];

    float* out = (float*)d_out;
    float* ws  = (float*)d_ws;
    unsigned* wsw  = (unsigned*)ws;                // 256 B f16 weight table (pad 512 floats)
    uint2*    T    = (uint2*)(ws + 512);           // B*N uint2 (4 MB)
    float*    part = ws + 512 + (size_t)B * N * 2; // B*S_CHUNKS*128 floats

    triple_kernel<<<(B * N) / 256, 256, 0, stream>>>(X, W1, b1, gamma, beta, wsw, T);
    pair_kernel<<<dim3(B, S_CHUNKS), 256, 0, stream>>>(T, pairs, wsw, part);
    head_kernel<<<B, 256, 0, stream>>>(part, Wm1, bm1, Wm2, bm2, mem,
                                       out, out + (size_t)B * C);
}

// Round 13
// 37.033 us; speedup vs baseline: 1.0207x; 1.0207x over previous
//
#include <hip/hip_runtime.h>

#define B 256
#define N 2048
#define P 2048
#define C 10
#define S_CHUNKS 8
#define PPB (P / S_CHUNKS)     // 256 pairs per block
#define NIT (PPB / 32)         // 8 iterations; 32 pairs per block-iter
#define LN_EPS 1e-5f

typedef float v2f __attribute__((ext_vector_type(2)));
typedef _Float16 h2 __attribute__((ext_vector_type(2)));

// ---- f16 helpers (proven R11/R12) ------------------------------------------
static __device__ __forceinline__ float fdot2(h2 a, h2 b, float c) {
#if __has_builtin(__builtin_amdgcn_fdot2)
    return __builtin_amdgcn_fdot2(a, b, c, false);   // v_dot2_f32_f16
#else
    return (float)a.x * (float)b.x + (float)a.y * (float)b.y + c;
#endif
}
static __device__ __forceinline__ h2 h2fma(h2 a, h2 b, h2 c) {
#if __has_builtin(__builtin_elementwise_fma)
    return __builtin_elementwise_fma(a, b, c);        // v_pk_fma_f16
#else
    return a * b + c;
#endif
}
static __device__ __forceinline__ h2 h2relu(h2 x) {
#if __has_builtin(__builtin_elementwise_max)
    return __builtin_elementwise_max(x, h2{(_Float16)0.f, (_Float16)0.f});
#else
    h2 r;
    r.x = x.x > (_Float16)0.f ? x.x : (_Float16)0.f;
    r.y = x.y > (_Float16)0.f ? x.y : (_Float16)0.f;
    return r;
#endif
}
static __device__ __forceinline__ h2 pkrtz(float a, float b) {
#if __has_builtin(__builtin_amdgcn_cvt_pkrtz)
    return __builtin_bit_cast(h2, __builtin_amdgcn_cvt_pkrtz(a, b));
#else
    return h2{(_Float16)a, (_Float16)b};
#endif
}
static __device__ __forceinline__ unsigned pk_rne(float a, float b) {
    return __builtin_bit_cast(unsigned, h2{(_Float16)a, (_Float16)b});
}

// ---- 16-lane all-reduce sum via DPP butterfly (proven R2..R12) --------------
static __device__ __forceinline__ float red16(float x) {
    x += __int_as_float(__builtin_amdgcn_update_dpp(0, __float_as_int(x), 0xB1,  0xF, 0xF, true));
    x += __int_as_float(__builtin_amdgcn_update_dpp(0, __float_as_int(x), 0x4E,  0xF, 0xF, true));
    x += __int_as_float(__builtin_amdgcn_update_dpp(0, __float_as_int(x), 0x141, 0xF, 0xF, true));
    x += __int_as_float(__builtin_amdgcn_update_dpp(0, __float_as_int(x), 0x140, 0xF, 0xF, true));
    return x;
}

// ---------------------------------------------------------------------------
// Kernel 1 (unchanged from R12): 6 variance-quadratic scalars reduced
// redundantly per block; block 0 writes the f16 per-sublane weight table;
// all blocks write T = {pk(rs*x0, rs*x1), pk(rs, 1)}.
// ---------------------------------------------------------------------------
__global__ __launch_bounds__(256) void triple_kernel(
        const float* __restrict__ X,
        const float* __restrict__ W1, const float* __restrict__ b1,
        const float* __restrict__ gamma, const float* __restrict__ beta,
        unsigned* __restrict__ wsw, uint2* __restrict__ T) {
    const int t = threadIdx.x;
    __shared__ float r[6][128];
    __shared__ float sc[6];

    float w0 = 0.f, w1 = 0.f, bb = 0.f;
    if (t < 128) {
        w0 = W1[t]; w1 = W1[128 + t]; bb = b1[t];
        r[0][t] = w0; r[1][t] = w1; r[2][t] = bb;
    }
    __syncthreads();
    for (int s = 64; s > 0; s >>= 1) {
        if (t < s) { r[0][t] += r[0][t + s]; r[1][t] += r[1][t + s]; r[2][t] += r[2][t + s]; }
        __syncthreads();
    }
    const float m0 = r[0][0] * (1.f / 128.f);
    const float m1 = r[1][0] * (1.f / 128.f);
    const float mb = r[2][0] * (1.f / 128.f);
    __syncthreads();
    float c0 = 0.f, c1 = 0.f, cb = 0.f;
    if (t < 128) {
        c0 = w0 - m0; c1 = w1 - m1; cb = bb - mb;
        r[0][t] = c0 * c0; r[1][t] = c1 * c1; r[2][t] = cb * cb;
        r[3][t] = c0 * c1; r[4][t] = c0 * cb; r[5][t] = c1 * cb;
    }
    __syncthreads();
    for (int s = 64; s > 0; s >>= 1) {
        if (t < s) {
            #pragma unroll
            for (int q = 0; q < 6; ++q) r[q][t] += r[q][t + s];
        }
        __syncthreads();
    }
    if (t < 6) sc[t] = r[t][0] * (1.f / 128.f);
    __syncthreads();

    const float S00 = sc[0], S11 = sc[1], Sbb = sc[2];
    const float S01 = sc[3], S0b = sc[4], S1b = sc[5];

    if (t < 128) {
        const float g = gamma[t];
        r[0][t] = g * c0; r[1][t] = g * c1; r[2][t] = g * cb; r[3][t] = beta[t];
    }
    __syncthreads();
    if (blockIdx.x == 0 && t < 16) {
        uint4* dst = (uint4*)wsw + t * 4;
        #pragma unroll
        for (int m = 0; m < 4; ++m) {
            const int d0 = t + 32 * m, d1 = d0 + 16;
            dst[m] = uint4{pk_rne(r[0][d0], r[0][d1]), pk_rne(r[1][d0], r[1][d1]),
                           pk_rne(r[2][d0], r[2][d1]), pk_rne(r[3][d0], r[3][d1])};
        }
    }

    const int gid = blockIdx.x * 256 + t;       // 0 .. B*N-1
    const float2 x = ((const float2*)X)[gid];
    const float v = fmaf(x.x * x.x, S00, fmaf(x.y * x.y, S11, Sbb))
                  + 2.f * fmaf(x.x * x.y, S01, fmaf(x.x, S0b, x.y * S1b));
    const float rs = rsqrtf(v + LN_EPS);
    T[gid] = uint2{pk_rne(rs * x.x, rs * x.y), pk_rne(rs, 1.f)};
}

// ---------------------------------------------------------------------------
// Kernel 2: f16 m-loop with LDS-staged T slice (16 KB, kills L1 thrash).
// 256 threads, grid (B, 8). 16-lane group = 1 pair per proc, 2 procs/iter.
// Reduce scratch aliases the stage buffer after a barrier.
// ---------------------------------------------------------------------------
__global__ __launch_bounds__(256) void pair_kernel(
        const uint2*    __restrict__ T,
        const int*      __restrict__ pairs,
        const unsigned* __restrict__ wsw,
        float* __restrict__ part) {
    const int b = blockIdx.x;
    const int chunk = blockIdx.y;
    const int tid = threadIdx.x;
    const int w = tid >> 6, l = tid & 63, g = l >> 4, s = l & 15;
    const int slot = w * 4 + g;      // 0..15

    // 16 KB shared: staged T slice, later aliased as reduce scratch (8.7 KB)
    __shared__ __align__(16) float lds[4096];
    uint2* Tl = (uint2*)lds;

    // stage T_b: 2048 uint2 = 1024 uint4; 256 threads x 4 uint4, coalesced
    {
        const uint4* Tb4 = (const uint4*)(T + (size_t)b * N);
        uint4* Tl4 = (uint4*)lds;
        #pragma unroll
        for (int q = 0; q < 4; ++q) Tl4[q * 256 + tid] = Tb4[q * 256 + tid];
    }

    // per-lane packed f16 weights: 4x dwordx4 (16 VGPRs)
    const uint4* Wl = (const uint4*)wsw + s * 4;
    h2 gw0[4], gw1[4], gbc[4], be2[4];
    #pragma unroll
    for (int m = 0; m < 4; ++m) {
        const uint4 wm = Wl[m];
        gw0[m] = __builtin_bit_cast(h2, wm.x);
        gw1[m] = __builtin_bit_cast(h2, wm.y);
        gbc[m] = __builtin_bit_cast(h2, wm.z);
        be2[m] = __builtin_bit_cast(h2, wm.w);
    }

    const int4* pr4 = (const int4*)pairs;      // 2 pairs per int4
    const int i4base = chunk * (PPB / 2);
    int4 idx = pr4[i4base + slot];             // prefetched 1 iter ahead

    v2f acc[4];
    #pragma unroll
    for (int m = 0; m < 4; ++m) acc[m] = v2f{0.f, 0.f};

    auto proc = [&](const uint2 ti, const uint2 tj) {
        const h2 abi = __builtin_bit_cast(h2, ti.x), ci = __builtin_bit_cast(h2, ti.y);
        const h2 abj = __builtin_bit_cast(h2, tj.x), cj = __builtin_bit_cast(h2, tj.y);
        const h2 aai = h2{abi.x, abi.x}, bbi = h2{abi.y, abi.y}, cci = h2{ci.x, ci.x};
        const h2 aaj = h2{abj.x, abj.x}, bbj = h2{abj.y, abj.y}, ccj = h2{cj.x, cj.x};
        h2 uu[4], vv[4];
        float nu0 = 0.f, nu1 = 0.f, nv0 = 0.f, nv1 = 0.f;   // split chains
        #pragma unroll
        for (int m = 0; m < 4; ++m) {
            const h2 hi = h2relu(h2fma(aai, gw0[m], h2fma(bbi, gw1[m], h2fma(cci, gbc[m], be2[m]))));
            const h2 hj = h2relu(h2fma(aaj, gw0[m], h2fma(bbj, gw1[m], h2fma(ccj, gbc[m], be2[m]))));
            const h2 u = hi - hj;
            const h2 v = hi + hj;
            if (m & 1) { nu1 = fdot2(u, u, nu1); nv1 = fdot2(v, v, nv1); }
            else       { nu0 = fdot2(u, u, nu0); nv0 = fdot2(v, v, nv0); }
            uu[m] = u; vv[m] = v;
        }
        const float nu = red16(nu0 + nu1);
        const float nv = red16(nv0 + nv1);
        const float ru = rsqrtf(fmaxf(nu, 1e-24f));
        const float rv = rsqrtf(fmaxf(nv, 1e-24f));
        const h2 ruv = pkrtz(ru, rv);
        #pragma unroll
        for (int m = 0; m < 4; ++m) {
            acc[m].x = fdot2(h2{uu[m].x, vv[m].x}, ruv, acc[m].x);
            acc[m].y = fdot2(h2{uu[m].y, vv[m].y}, ruv, acc[m].y);
        }
    };

    __syncthreads();                           // T staged

    for (int t = 0; t < NIT; ++t) {
        const int4 nidx = (t + 1 < NIT) ? pr4[i4base + (t + 1) * 16 + slot] : idx;
        const uint2 tiA = Tl[idx.x], tjA = Tl[idx.y];
        const uint2 tiB = Tl[idx.z], tjB = Tl[idx.w];
        proc(tiA, tjA);
        proc(tiB, tjB);
        idx = nidx;
    }

    __syncthreads();                           // done reading staged T

    // reduce scratch aliases stage buffer: [slot][k][s] = lds[slot*136+k*17+s]
    #pragma unroll
    for (int m = 0; m < 4; ++m) {
        lds[slot * 136 + (2 * m)     * 17 + s] = acc[m].x;   // d = s + 32m
        lds[slot * 136 + (2 * m + 1) * 17 + s] = acc[m].y;   // d = s + 32m + 16
    }
    __syncthreads();
    if (tid < 128) {
        const int ss = tid & 15, kk = tid >> 4;   // d = ss + 16*kk == tid
        float sum = 0.f;
        #pragma unroll
        for (int q = 0; q < 16; ++q) sum += lds[q * 136 + kk * 17 + ss];
        part[((size_t)b * S_CHUNKS + chunk) * 128 + tid] = sum;
    }
}

// ---------------------------------------------------------------------------
// Kernel 3: reduce partials -> sdi, MLP head + mem logits.
// ---------------------------------------------------------------------------
__global__ __launch_bounds__(256) void head_kernel(
        const float* __restrict__ part,
        const float* __restrict__ Wm1, const float* __restrict__ bm1,
        const float* __restrict__ Wm2, const float* __restrict__ bm2,
        const float* __restrict__ mem,
        float* __restrict__ out_logits, float* __restrict__ out_sdi) {
    const int b = blockIdx.x;
    const int t = threadIdx.x;
    __shared__ float s[128];
    __shared__ float h[128];

    if (t < 128) {
        float sv = 0.f;
        #pragma unroll
        for (int k = 0; k < S_CHUNKS; ++k)
            sv += part[((size_t)b * S_CHUNKS + k) * 128 + t];
        sv *= (1.f / (2.f * P));
        s[t] = sv;
        out_sdi[(size_t)b * 128 + t] = sv;
    }
    __syncthreads();
    if (t < 128) {
        float a = bm1[t];
        for (int d = 0; d < 128; ++d) a = fmaf(s[d], Wm1[d * 128 + t], a);
        h[t] = fmaxf(a, 0.f);
    }
    __syncthreads();
    if (t < 16 * C) {                       // 160 threads: 16 lanes per class
        const int c = t >> 4, l = t & 15;
        float lg = 0.f;
        #pragma unroll
        for (int q = 0; q < 8; ++q) {
            const int d = l + 16 * q;
            lg = fmaf(s[d], mem[c * 128 + d], fmaf(h[d], Wm2[d * C + c], lg));
        }
        lg = red16(lg);
        if (l == 0) out_logits[(size_t)b * C + c] = lg + bm2[c];
    }
}

extern "C" void kernel_launch(void* const* d_in, const int* in_sizes, int n_in,
                              void* d_out, int out_size, void* d_ws, size_t ws_size,
                              hipStream_t stream) {
    const float* X     = (const float*)d_in[0];
    const int*   pairs = (const int*)  d_in[1];
    const float* W1    = (const float*)d_in[2];
    const float* b1    = (const float*)d_in[3];
    const float* gamma = (const float*)d_in[4];
    const float* beta  = (const float*)d_in[5];
    const float* Wm1   = (const float*)d_in[6];
    const float* bm1   = (const float*)d_in[7];
    const float* Wm2   = (const float*)d_in[8];
    const float* bm2   = (const float*)d_in[9];
    const float* mem   = (const float*)d_in[10];

    float* out = (float*)d_out;
    float* ws  = (float*)d_ws;
    unsigned* wsw  = (unsigned*)ws;                // f16 weight table (512-float pad)
    uint2*    T    = (uint2*)(ws + 512);           // B*N uint2 (4 MB)
    float*    part = ws + 512 + (size_t)B * N * 2; // B*S_CHUNKS*128 floats (1 MB)

    triple_kernel<<<(B * N) / 256, 256, 0, stream>>>(X, W1, b1, gamma, beta, wsw, T);
    pair_kernel<<<dim3(B, S_CHUNKS), 256, 0, stream>>>(T, pairs, wsw, part);
    head_kernel<<<B, 256, 0, stream>>>(part, Wm1, bm1, Wm2, bm2, mem,
                                       out, out + (size_t)B * C);
}

// Round 14
// 36.730 us; speedup vs baseline: 1.0291x; 1.0082x over previous
//
#include <hip/hip_runtime.h>

#define B 256
#define N 2048
#define P 2048
#define C 10
#define S_CHUNKS 8
#define PPB (P / S_CHUNKS)     // 256 pairs per block
#define NIT (PPB / 32)         // 8 iterations; 32 pairs per block-iter
#define LN_EPS 1e-5f

typedef float v2f __attribute__((ext_vector_type(2)));
typedef _Float16 h2 __attribute__((ext_vector_type(2)));

// ---- f16 helpers (proven R11..R13) ------------------------------------------
static __device__ __forceinline__ float fdot2(h2 a, h2 b, float c) {
#if __has_builtin(__builtin_amdgcn_fdot2)
    return __builtin_amdgcn_fdot2(a, b, c, false);   // v_dot2_f32_f16
#else
    return (float)a.x * (float)b.x + (float)a.y * (float)b.y + c;
#endif
}
static __device__ __forceinline__ h2 h2fma(h2 a, h2 b, h2 c) {
#if __has_builtin(__builtin_elementwise_fma)
    return __builtin_elementwise_fma(a, b, c);        // v_pk_fma_f16
#else
    return a * b + c;
#endif
}
static __device__ __forceinline__ h2 h2relu(h2 x) {
#if __has_builtin(__builtin_elementwise_max)
    return __builtin_elementwise_max(x, h2{(_Float16)0.f, (_Float16)0.f});
#else
    h2 r;
    r.x = x.x > (_Float16)0.f ? x.x : (_Float16)0.f;
    r.y = x.y > (_Float16)0.f ? x.y : (_Float16)0.f;
    return r;
#endif
}
static __device__ __forceinline__ h2 pkrtz(float a, float b) {
#if __has_builtin(__builtin_amdgcn_cvt_pkrtz)
    return __builtin_bit_cast(h2, __builtin_amdgcn_cvt_pkrtz(a, b));
#else
    return h2{(_Float16)a, (_Float16)b};
#endif
}
static __device__ __forceinline__ unsigned pk_rne(float a, float b) {
    return __builtin_bit_cast(unsigned, h2{(_Float16)a, (_Float16)b});
}

// ---- 16-lane all-reduce sum via DPP butterfly (proven R2..R13) --------------
static __device__ __forceinline__ float red16(float x) {
    x += __int_as_float(__builtin_amdgcn_update_dpp(0, __float_as_int(x), 0xB1,  0xF, 0xF, true));
    x += __int_as_float(__builtin_amdgcn_update_dpp(0, __float_as_int(x), 0x4E,  0xF, 0xF, true));
    x += __int_as_float(__builtin_amdgcn_update_dpp(0, __float_as_int(x), 0x141, 0xF, 0xF, true));
    x += __int_as_float(__builtin_amdgcn_update_dpp(0, __float_as_int(x), 0x140, 0xF, 0xF, true));
    return x;
}

// ---------------------------------------------------------------------------
// Kernel 1 (unchanged): per-block redundant 6-scalar reduction; block 0
// writes the f16 per-sublane weight table; all blocks write
// T = {pk(rs*x0, rs*x1), pk(rs, 1)}.
// ---------------------------------------------------------------------------
__global__ __launch_bounds__(256) void triple_kernel(
        const float* __restrict__ X,
        const float* __restrict__ W1, const float* __restrict__ b1,
        const float* __restrict__ gamma, const float* __restrict__ beta,
        unsigned* __restrict__ wsw, uint2* __restrict__ T) {
    const int t = threadIdx.x;
    __shared__ float r[6][128];
    __shared__ float sc[6];

    float w0 = 0.f, w1 = 0.f, bb = 0.f;
    if (t < 128) {
        w0 = W1[t]; w1 = W1[128 + t]; bb = b1[t];
        r[0][t] = w0; r[1][t] = w1; r[2][t] = bb;
    }
    __syncthreads();
    for (int s = 64; s > 0; s >>= 1) {
        if (t < s) { r[0][t] += r[0][t + s]; r[1][t] += r[1][t + s]; r[2][t] += r[2][t + s]; }
        __syncthreads();
    }
    const float m0 = r[0][0] * (1.f / 128.f);
    const float m1 = r[1][0] * (1.f / 128.f);
    const float mb = r[2][0] * (1.f / 128.f);
    __syncthreads();
    float c0 = 0.f, c1 = 0.f, cb = 0.f;
    if (t < 128) {
        c0 = w0 - m0; c1 = w1 - m1; cb = bb - mb;
        r[0][t] = c0 * c0; r[1][t] = c1 * c1; r[2][t] = cb * cb;
        r[3][t] = c0 * c1; r[4][t] = c0 * cb; r[5][t] = c1 * cb;
    }
    __syncthreads();
    for (int s = 64; s > 0; s >>= 1) {
        if (t < s) {
            #pragma unroll
            for (int q = 0; q < 6; ++q) r[q][t] += r[q][t + s];
        }
        __syncthreads();
    }
    if (t < 6) sc[t] = r[t][0] * (1.f / 128.f);
    __syncthreads();

    const float S00 = sc[0], S11 = sc[1], Sbb = sc[2];
    const float S01 = sc[3], S0b = sc[4], S1b = sc[5];

    if (t < 128) {
        const float g = gamma[t];
        r[0][t] = g * c0; r[1][t] = g * c1; r[2][t] = g * cb; r[3][t] = beta[t];
    }
    __syncthreads();
    if (blockIdx.x == 0 && t < 16) {
        uint4* dst = (uint4*)wsw + t * 4;
        #pragma unroll
        for (int m = 0; m < 4; ++m) {
            const int d0 = t + 32 * m, d1 = d0 + 16;
            dst[m] = uint4{pk_rne(r[0][d0], r[0][d1]), pk_rne(r[1][d0], r[1][d1]),
                           pk_rne(r[2][d0], r[2][d1]), pk_rne(r[3][d0], r[3][d1])};
        }
    }

    const int gid = blockIdx.x * 256 + t;       // 0 .. B*N-1
    const float2 x = ((const float2*)X)[gid];
    const float v = fmaf(x.x * x.x, S00, fmaf(x.y * x.y, S11, Sbb))
                  + 2.f * fmaf(x.x * x.y, S01, fmaf(x.x, S0b, x.y * S1b));
    const float rs = rsqrtf(v + LN_EPS);
    T[gid] = uint2{pk_rne(rs * x.x, rs * x.y), pk_rne(rs, 1.f)};
}

// ---------------------------------------------------------------------------
// Kernel 2: LDS-staged T + 3-stage software pipeline:
//   idx prefetched 2 iters ahead (global, ~640 cyc cover),
//   data ds_read 1 iter ahead (~320 cyc cover vs ~120 cyc LDS latency).
// 256 threads, grid (B, 8); 16-lane group = 1 pair per proc, 2 procs/iter.
// ---------------------------------------------------------------------------
__global__ __launch_bounds__(256) void pair_kernel(
        const uint2*    __restrict__ T,
        const int*      __restrict__ pairs,
        const unsigned* __restrict__ wsw,
        float* __restrict__ part) {
    const int b = blockIdx.x;
    const int chunk = blockIdx.y;
    const int tid = threadIdx.x;
    const int w = tid >> 6, l = tid & 63, g = l >> 4, s = l & 15;
    const int slot = w * 4 + g;      // 0..15

    // 16 KB shared: staged T slice, later aliased as reduce scratch (8.7 KB)
    __shared__ __align__(16) float lds[4096];
    uint2* Tl = (uint2*)lds;

    // stage T_b: 2048 uint2 = 1024 uint4; 256 threads x 4 uint4, coalesced
    {
        const uint4* Tb4 = (const uint4*)(T + (size_t)b * N);
        uint4* Tl4 = (uint4*)lds;
        #pragma unroll
        for (int q = 0; q < 4; ++q) Tl4[q * 256 + tid] = Tb4[q * 256 + tid];
    }

    // per-lane packed f16 weights: 4x dwordx4 (16 VGPRs)
    const uint4* Wl = (const uint4*)wsw + s * 4;
    h2 gw0[4], gw1[4], gbc[4], be2[4];
    #pragma unroll
    for (int m = 0; m < 4; ++m) {
        const uint4 wm = Wl[m];
        gw0[m] = __builtin_bit_cast(h2, wm.x);
        gw1[m] = __builtin_bit_cast(h2, wm.y);
        gbc[m] = __builtin_bit_cast(h2, wm.z);
        be2[m] = __builtin_bit_cast(h2, wm.w);
    }

    const int4* pr4 = (const int4*)pairs;      // 2 pairs per int4
    const int i4base = chunk * (PPB / 2);

    v2f acc[4];
    #pragma unroll
    for (int m = 0; m < 4; ++m) acc[m] = v2f{0.f, 0.f};

    auto proc = [&](const uint2 ti, const uint2 tj) {
        const h2 abi = __builtin_bit_cast(h2, ti.x), ci = __builtin_bit_cast(h2, ti.y);
        const h2 abj = __builtin_bit_cast(h2, tj.x), cj = __builtin_bit_cast(h2, tj.y);
        const h2 aai = h2{abi.x, abi.x}, bbi = h2{abi.y, abi.y}, cci = h2{ci.x, ci.x};
        const h2 aaj = h2{abj.x, abj.x}, bbj = h2{abj.y, abj.y}, ccj = h2{cj.x, cj.x};
        h2 uu[4], vv[4];
        float nu0 = 0.f, nu1 = 0.f, nv0 = 0.f, nv1 = 0.f;   // split chains
        #pragma unroll
        for (int m = 0; m < 4; ++m) {
            const h2 hi = h2relu(h2fma(aai, gw0[m], h2fma(bbi, gw1[m], h2fma(cci, gbc[m], be2[m]))));
            const h2 hj = h2relu(h2fma(aaj, gw0[m], h2fma(bbj, gw1[m], h2fma(ccj, gbc[m], be2[m]))));
            const h2 u = hi - hj;
            const h2 v = hi + hj;
            if (m & 1) { nu1 = fdot2(u, u, nu1); nv1 = fdot2(v, v, nv1); }
            else       { nu0 = fdot2(u, u, nu0); nv0 = fdot2(v, v, nv0); }
            uu[m] = u; vv[m] = v;
        }
        const float nu = red16(nu0 + nu1);
        const float nv = red16(nv0 + nv1);
        const float ru = rsqrtf(fmaxf(nu, 1e-24f));
        const float rv = rsqrtf(fmaxf(nv, 1e-24f));
        const h2 ruv = pkrtz(ru, rv);
        #pragma unroll
        for (int m = 0; m < 4; ++m) {
            acc[m].x = fdot2(h2{uu[m].x, vv[m].x}, ruv, acc[m].x);
            acc[m].y = fdot2(h2{uu[m].y, vv[m].y}, ruv, acc[m].y);
        }
    };

    // ---- pipeline prologue ----
    const int4 idx0 = pr4[i4base + slot];                  // iter 0 (pre-barrier)
    __syncthreads();                                       // T staged
    int4 idxN = pr4[i4base + 16 + slot];                   // iter 1
    uint2 tiA = Tl[idx0.x], tjA = Tl[idx0.y];              // data for iter 0
    uint2 tiB = Tl[idx0.z], tjB = Tl[idx0.w];

    for (int t = 0; t < NIT; ++t) {
        // data for t+1 (ds_read, covered by the 2 procs below)
        const uint2 ntiA = Tl[idxN.x], ntjA = Tl[idxN.y];
        const uint2 ntiB = Tl[idxN.z], ntjB = Tl[idxN.w];
        // idx for t+2 (global, covered by ~2 iterations)
        const int t2 = (t + 2 < NIT) ? (t + 2) : (NIT - 1);
        const int4 idxNN = pr4[i4base + t2 * 16 + slot];

        proc(tiA, tjA);
        proc(tiB, tjB);

        tiA = ntiA; tjA = ntjA; tiB = ntiB; tjB = ntjB;
        idxN = idxNN;
    }

    __syncthreads();                           // done reading staged T

    // reduce scratch aliases stage buffer: [slot][k][s] = lds[slot*136+k*17+s]
    #pragma unroll
    for (int m = 0; m < 4; ++m) {
        lds[slot * 136 + (2 * m)     * 17 + s] = acc[m].x;   // d = s + 32m
        lds[slot * 136 + (2 * m + 1) * 17 + s] = acc[m].y;   // d = s + 32m + 16
    }
    __syncthreads();
    if (tid < 128) {
        const int ss = tid & 15, kk = tid >> 4;   // d = ss + 16*kk == tid
        float sum = 0.f;
        #pragma unroll
        for (int q = 0; q < 16; ++q) sum += lds[q * 136 + kk * 17 + ss];
        part[((size_t)b * S_CHUNKS + chunk) * 128 + tid] = sum;
    }
}

// ---------------------------------------------------------------------------
// Kernel 3: reduce partials -> sdi, MLP head + mem logits.
// ---------------------------------------------------------------------------
__global__ __launch_bounds__(256) void head_kernel(
        const float* __restrict__ part,
        const float* __restrict__ Wm1, const float* __restrict__ bm1,
        const float* __restrict__ Wm2, const float* __restrict__ bm2,
        const float* __restrict__ mem,
        float* __restrict__ out_logits, float* __restrict__ out_sdi) {
    const int b = blockIdx.x;
    const int t = threadIdx.x;
    __shared__ float s[128];
    __shared__ float h[128];

    if (t < 128) {
        float sv = 0.f;
        #pragma unroll
        for (int k = 0; k < S_CHUNKS; ++k)
            sv += part[((size_t)b * S_CHUNKS + k) * 128 + t];
        sv *= (1.f / (2.f * P));
        s[t] = sv;
        out_sdi[(size_t)b * 128 + t] = sv;
    }
    __syncthreads();
    if (t < 128) {
        float a = bm1[t];
        for (int d = 0; d < 128; ++d) a = fmaf(s[d], Wm1[d * 128 + t], a);
        h[t] = fmaxf(a, 0.f);
    }
    __syncthreads();
    if (t < 16 * C) {                       // 160 threads: 16 lanes per class
        const int c = t >> 4, l = t & 15;
        float lg = 0.f;
        #pragma unroll
        for (int q = 0; q < 8; ++q) {
            const int d = l + 16 * q;
            lg = fmaf(s[d], mem[c * 128 + d], fmaf(h[d], Wm2[d * C + c], lg));
        }
        lg = red16(lg);
        if (l == 0) out_logits[(size_t)b * C + c] = lg + bm2[c];
    }
}

extern "C" void kernel_launch(void* const* d_in, const int* in_sizes, int n_in,
                              void* d_out, int out_size, void* d_ws, size_t ws_size,
                              hipStream_t stream) {
    const float* X     = (const float*)d_in[0];
    const int*   pairs = (const int*)  d_in[1];
    const float* W1    = (const float*)d_in[2];
    const float* b1    = (const float*)d_in[3];
    const float* gamma = (const float*)d_in[4];
    const float* beta  = (const float*)d_in[5];
    const float* Wm1   = (const float*)d_in[6];
    const float* bm1   = (const float*)d_in[7];
    const float* Wm2   = (const float*)d_in[8];
    const float* bm2   = (const float*)d_in[9];
    const float* mem   = (const float*)d_in[10];

    float* out = (float*)d_out;
    float* ws  = (float*)d_ws;
    unsigned* wsw  = (unsigned*)ws;                // f16 weight table (512-float pad)
    uint2*    T    = (uint2*)(ws + 512);           // B*N uint2 (4 MB)
    float*    part = ws + 512 + (size_t)B * N * 2; // B*S_CHUNKS*128 floats (1 MB)

    triple_kernel<<<(B * N) / 256, 256, 0, stream>>>(X, W1, b1, gamma, beta, wsw, T);
    pair_kernel<<<dim3(B, S_CHUNKS), 256, 0, stream>>>(T, pairs, wsw, part);
    head_kernel<<<B, 256, 0, stream>>>(part, Wm1, bm1, Wm2, bm2, mem,
                                       out, out + (size_t)B * C);
}

// Round 15
// 32.424 us; speedup vs baseline: 1.1657x; 1.1328x over previous
//
#include <hip/hip_runtime.h>

#define B 256
#define N 2048
#define P 2048
#define C 10
#define S_CHUNKS 4
#define PPB (P / S_CHUNKS)     // 512 pairs per block
#define NIT (PPB / 32)         // 16 iterations; 32 pairs per block-iter
#define LN_EPS 1e-5f

typedef float v2f __attribute__((ext_vector_type(2)));
typedef _Float16 h2 __attribute__((ext_vector_type(2)));

// ---- f16 helpers (proven R11..R14) ------------------------------------------
static __device__ __forceinline__ float fdot2(h2 a, h2 b, float c) {
#if __has_builtin(__builtin_amdgcn_fdot2)
    return __builtin_amdgcn_fdot2(a, b, c, false);   // v_dot2_f32_f16
#else
    return (float)a.x * (float)b.x + (float)a.y * (float)b.y + c;
#endif
}
static __device__ __forceinline__ h2 h2fma(h2 a, h2 b, h2 c) {
#if __has_builtin(__builtin_elementwise_fma)
    return __builtin_elementwise_fma(a, b, c);        // v_pk_fma_f16
#else
    return a * b + c;
#endif
}
static __device__ __forceinline__ h2 h2relu(h2 x) {
#if __has_builtin(__builtin_elementwise_max)
    return __builtin_elementwise_max(x, h2{(_Float16)0.f, (_Float16)0.f});
#else
    h2 r;
    r.x = x.x > (_Float16)0.f ? x.x : (_Float16)0.f;
    r.y = x.y > (_Float16)0.f ? x.y : (_Float16)0.f;
    return r;
#endif
}
static __device__ __forceinline__ h2 pkrtz(float a, float b) {
#if __has_builtin(__builtin_amdgcn_cvt_pkrtz)
    return __builtin_bit_cast(h2, __builtin_amdgcn_cvt_pkrtz(a, b));
#else
    return h2{(_Float16)a, (_Float16)b};
#endif
}
static __device__ __forceinline__ unsigned pk_rne(float a, float b) {
    return __builtin_bit_cast(unsigned, h2{(_Float16)a, (_Float16)b});
}

// ---- 16-lane all-reduce sum via DPP butterfly (proven R2..R14) --------------
static __device__ __forceinline__ float red16(float x) {
    x += __int_as_float(__builtin_amdgcn_update_dpp(0, __float_as_int(x), 0xB1,  0xF, 0xF, true));
    x += __int_as_float(__builtin_amdgcn_update_dpp(0, __float_as_int(x), 0x4E,  0xF, 0xF, true));
    x += __int_as_float(__builtin_amdgcn_update_dpp(0, __float_as_int(x), 0x141, 0xF, 0xF, true));
    x += __int_as_float(__builtin_amdgcn_update_dpp(0, __float_as_int(x), 0x140, 0xF, 0xF, true));
    return x;
}

// ---------------------------------------------------------------------------
// Fused kernel: per block (b, chunk):
//   1. wave 0 reduces means + 6 variance-quadratic scalars via __shfl_xor
//   2. all threads build gamma-folded weight arrays (f32, LDS) and the
//      T slice for batch b directly from X into LDS (f16-packed)
//   3. R14 pair loop (LDS gathers, pipelined), partial sdi out.
// ---------------------------------------------------------------------------
__global__ __launch_bounds__(256) void fused_kernel(
        const float* __restrict__ X,
        const float* __restrict__ W1, const float* __restrict__ b1,
        const float* __restrict__ gamma, const float* __restrict__ beta,
        const int*   __restrict__ pairs,
        float* __restrict__ part) {
    const int b = blockIdx.x;
    const int chunk = blockIdx.y;
    const int tid = threadIdx.x;
    const int w = tid >> 6, l = tid & 63, g = l >> 4, s = l & 15;
    const int slot = w * 4 + g;      // 0..15

    __shared__ __align__(16) float lds[4096];  // 16 KB: T stage + reduce alias
    __shared__ float wf[4][128];                // gamma-folded weights + beta
    __shared__ float sc[9];                     // S00,S11,Sbb,S01,S0b,S1b,m0,m1,mb
    uint2* Tl = (uint2*)lds;

    // ---- step 1: wave 0 computes the 9 scalars ----
    if (w == 0) {
        const float w0a = W1[l],       w0b = W1[l + 64];
        const float w1a = W1[128 + l], w1b = W1[128 + l + 64];
        const float bba = b1[l],       bbb = b1[l + 64];
        float s0 = w0a + w0b, s1 = w1a + w1b, sb = bba + bbb;
        #pragma unroll
        for (int m = 1; m < 64; m <<= 1) {
            s0 += __shfl_xor(s0, m);
            s1 += __shfl_xor(s1, m);
            sb += __shfl_xor(sb, m);
        }
        const float m0 = s0 * (1.f / 128.f);
        const float m1 = s1 * (1.f / 128.f);
        const float mb = sb * (1.f / 128.f);
        const float c0a = w0a - m0, c0b = w0b - m0;
        const float c1a = w1a - m1, c1b = w1b - m1;
        const float cba = bba - mb, cbb = bbb - mb;
        float q[6] = { c0a*c0a + c0b*c0b, c1a*c1a + c1b*c1b, cba*cba + cbb*cbb,
                       c0a*c1a + c0b*c1b, c0a*cba + c0b*cbb, c1a*cba + c1b*cbb };
        #pragma unroll
        for (int m = 1; m < 64; m <<= 1) {
            #pragma unroll
            for (int k = 0; k < 6; ++k) q[k] += __shfl_xor(q[k], m);
        }
        if (l < 6) sc[l] = q[l] * (1.f / 128.f);   // lane 0..5 write (all lanes hold all sums)
        if (l == 6) sc[6] = m0;
        if (l == 7) sc[7] = m1;
        if (l == 8) sc[8] = mb;
    }
    __syncthreads();

    // ---- step 2a: weight arrays (f32) ----
    if (tid < 128) {
        const float m0 = sc[6], m1 = sc[7], mb = sc[8];
        const float g_ = gamma[tid];
        wf[0][tid] = g_ * (W1[tid] - m0);
        wf[1][tid] = g_ * (W1[128 + tid] - m1);
        wf[2][tid] = g_ * (b1[tid] - mb);
        wf[3][tid] = beta[tid];
    }

    // ---- step 2b: T slice for batch b, straight from X ----
    {
        const float S00 = sc[0], S11 = sc[1], Sbb = sc[2];
        const float S01 = sc[3], S0b = sc[4], S1b = sc[5];
        const float2* Xb = (const float2*)(X + (size_t)b * N * 2);
        #pragma unroll
        for (int q = 0; q < 8; ++q) {
            const int n = q * 256 + tid;
            const float2 x = Xb[n];
            const float v = fmaf(x.x * x.x, S00, fmaf(x.y * x.y, S11, Sbb))
                          + 2.f * fmaf(x.x * x.y, S01, fmaf(x.x, S0b, x.y * S1b));
            const float rs = rsqrtf(v + LN_EPS);
            Tl[n] = uint2{pk_rne(rs * x.x, rs * x.y), pk_rne(rs, 1.f)};
        }
    }
    __syncthreads();

    // ---- per-lane packed f16 weights from LDS ----
    h2 gw0[4], gw1[4], gbc[4], be2[4];
    #pragma unroll
    for (int m = 0; m < 4; ++m) {
        const int d0 = s + 32 * m, d1 = d0 + 16;
        gw0[m] = h2{(_Float16)wf[0][d0], (_Float16)wf[0][d1]};
        gw1[m] = h2{(_Float16)wf[1][d0], (_Float16)wf[1][d1]};
        gbc[m] = h2{(_Float16)wf[2][d0], (_Float16)wf[2][d1]};
        be2[m] = h2{(_Float16)wf[3][d0], (_Float16)wf[3][d1]};
    }

    const int4* pr4 = (const int4*)pairs;      // 2 pairs per int4
    const int i4base = chunk * (PPB / 2);

    v2f acc[4];
    #pragma unroll
    for (int m = 0; m < 4; ++m) acc[m] = v2f{0.f, 0.f};

    auto proc = [&](const uint2 ti, const uint2 tj) {
        const h2 abi = __builtin_bit_cast(h2, ti.x), ci = __builtin_bit_cast(h2, ti.y);
        const h2 abj = __builtin_bit_cast(h2, tj.x), cj = __builtin_bit_cast(h2, tj.y);
        const h2 aai = h2{abi.x, abi.x}, bbi = h2{abi.y, abi.y}, cci = h2{ci.x, ci.x};
        const h2 aaj = h2{abj.x, abj.x}, bbj = h2{abj.y, abj.y}, ccj = h2{cj.x, cj.x};
        h2 uu[4], vv[4];
        float nu0 = 0.f, nu1 = 0.f, nv0 = 0.f, nv1 = 0.f;
        #pragma unroll
        for (int m = 0; m < 4; ++m) {
            const h2 hi = h2relu(h2fma(aai, gw0[m], h2fma(bbi, gw1[m], h2fma(cci, gbc[m], be2[m]))));
            const h2 hj = h2relu(h2fma(aaj, gw0[m], h2fma(bbj, gw1[m], h2fma(ccj, gbc[m], be2[m]))));
            const h2 u = hi - hj;
            const h2 v = hi + hj;
            if (m & 1) { nu1 = fdot2(u, u, nu1); nv1 = fdot2(v, v, nv1); }
            else       { nu0 = fdot2(u, u, nu0); nv0 = fdot2(v, v, nv0); }
            uu[m] = u; vv[m] = v;
        }
        const float nu = red16(nu0 + nu1);
        const float nv = red16(nv0 + nv1);
        const float ru = rsqrtf(fmaxf(nu, 1e-24f));
        const float rv = rsqrtf(fmaxf(nv, 1e-24f));
        const h2 ruv = pkrtz(ru, rv);
        #pragma unroll
        for (int m = 0; m < 4; ++m) {
            acc[m].x = fdot2(h2{uu[m].x, vv[m].x}, ruv, acc[m].x);
            acc[m].y = fdot2(h2{uu[m].y, vv[m].y}, ruv, acc[m].y);
        }
    };

    // ---- pipeline prologue (R14 structure) ----
    const int4 idx0 = pr4[i4base + slot];
    int4 idxN = pr4[i4base + 16 + slot];
    uint2 tiA = Tl[idx0.x], tjA = Tl[idx0.y];
    uint2 tiB = Tl[idx0.z], tjB = Tl[idx0.w];

    for (int t = 0; t < NIT; ++t) {
        const uint2 ntiA = Tl[idxN.x], ntjA = Tl[idxN.y];
        const uint2 ntiB = Tl[idxN.z], ntjB = Tl[idxN.w];
        const int t2 = (t + 2 < NIT) ? (t + 2) : (NIT - 1);
        const int4 idxNN = pr4[i4base + t2 * 16 + slot];

        proc(tiA, tjA);
        proc(tiB, tjB);

        tiA = ntiA; tjA = ntjA; tiB = ntiB; tjB = ntjB;
        idxN = idxNN;
    }

    __syncthreads();                           // done reading staged T

    // reduce scratch aliases stage buffer: [slot][k][s] = lds[slot*136+k*17+s]
    #pragma unroll
    for (int m = 0; m < 4; ++m) {
        lds[slot * 136 + (2 * m)     * 17 + s] = acc[m].x;   // d = s + 32m
        lds[slot * 136 + (2 * m + 1) * 17 + s] = acc[m].y;   // d = s + 32m + 16
    }
    __syncthreads();
    if (tid < 128) {
        const int ss = tid & 15, kk = tid >> 4;   // d = ss + 16*kk == tid
        float sum = 0.f;
        #pragma unroll
        for (int q = 0; q < 16; ++q) sum += lds[q * 136 + kk * 17 + ss];
        part[((size_t)b * S_CHUNKS + chunk) * 128 + tid] = sum;
    }
}

// ---------------------------------------------------------------------------
// Kernel 2: reduce partials -> sdi, MLP head + mem logits.
// ---------------------------------------------------------------------------
__global__ __launch_bounds__(256) void head_kernel(
        const float* __restrict__ part,
        const float* __restrict__ Wm1, const float* __restrict__ bm1,
        const float* __restrict__ Wm2, const float* __restrict__ bm2,
        const float* __restrict__ mem,
        float* __restrict__ out_logits, float* __restrict__ out_sdi) {
    const int b = blockIdx.x;
    const int t = threadIdx.x;
    __shared__ float s[128];
    __shared__ float h[128];

    if (t < 128) {
        float sv = 0.f;
        #pragma unroll
        for (int k = 0; k < S_CHUNKS; ++k)
            sv += part[((size_t)b * S_CHUNKS + k) * 128 + t];
        sv *= (1.f / (2.f * P));
        s[t] = sv;
        out_sdi[(size_t)b * 128 + t] = sv;
    }
    __syncthreads();
    if (t < 128) {
        float a = bm1[t];
        for (int d = 0; d < 128; ++d) a = fmaf(s[d], Wm1[d * 128 + t], a);
        h[t] = fmaxf(a, 0.f);
    }
    __syncthreads();
    if (t < 16 * C) {                       // 160 threads: 16 lanes per class
        const int c = t >> 4, l = t & 15;
        float lg = 0.f;
        #pragma unroll
        for (int q = 0; q < 8; ++q) {
            const int d = l + 16 * q;
            lg = fmaf(s[d], mem[c * 128 + d], fmaf(h[d], Wm2[d * C + c], lg));
        }
        lg = red16(lg);
        if (l == 0) out_logits[(size_t)b * C + c] = lg + bm2[c];
    }
}

extern "C" void kernel_launch(void* const* d_in, const int* in_sizes, int n_in,
                              void* d_out, int out_size, void* d_ws, size_t ws_size,
                              hipStream_t stream) {
    const float* X     = (const float*)d_in[0];
    const int*   pairs = (const int*)  d_in[1];
    const float* W1    = (const float*)d_in[2];
    const float* b1    = (const float*)d_in[3];
    const float* gamma = (const float*)d_in[4];
    const float* beta  = (const float*)d_in[5];
    const float* Wm1   = (const float*)d_in[6];
    const float* bm1   = (const float*)d_in[7];
    const float* Wm2   = (const float*)d_in[8];
    const float* bm2   = (const float*)d_in[9];
    const float* mem   = (const float*)d_in[10];

    float* out = (float*)d_out;
    float* part = (float*)d_ws;                // B*S_CHUNKS*128 floats (512 KB)

    fused_kernel<<<dim3(B, S_CHUNKS), 256, 0, stream>>>(X, W1, b1, gamma, beta,
                                                        pairs, part);
    head_kernel<<<B, 256, 0, stream>>>(part, Wm1, bm1, Wm2, bm2, mem,
                                       out, out + (size_t)B * C);
}